// Round 1
// baseline (1545.143 us; speedup 1.0000x reference)
//
#include <hip/hip_runtime.h>
#include <hip/hip_bf16.h>
#include <float.h>

#define N_FEAT 6272      // B*FH*FW = 8*28*28
#define N_FPAD 6400      // 25 * 256
#define C_DIM  1024
#define M_MEM  50000
#define M_PAD  50176     // 196 * 256
#define B_IMG  8
#define IMGSZ  224
#define NTM    25        // 6400/256
#define NTN    196       // 50176/256
#define NT     4900      // 25*196

typedef __attribute__((ext_vector_type(8))) short bf16x8;
typedef __attribute__((ext_vector_type(4))) float f32x4;

// ---------- helpers ----------

__device__ inline unsigned short f2bf(float x) {
  unsigned int u = __float_as_uint(x);
  u += 0x7FFFu + ((u >> 16) & 1u);
  return (unsigned short)(u >> 16);
}

// ---------- 1. fp32 -> bf16 conversion + row sum-of-squares (1 wave / row) ----------
__global__ __launch_bounds__(256) void convert_rows_kernel(
    const float* __restrict__ src, unsigned short* __restrict__ dst,
    float* __restrict__ sq, unsigned int* __restrict__ minbits,
    int valid_rows, int total_rows)
{
  int row  = blockIdx.x * 4 + (threadIdx.x >> 6);
  int lane = threadIdx.x & 63;
  if (row >= total_rows) return;
  float s = 0.f;
  ushort4* d4 = (ushort4*)(dst + (size_t)row * C_DIM);
  if (row < valid_rows) {
    const float4* s4 = (const float4*)(src + (size_t)row * C_DIM);
    #pragma unroll
    for (int j = 0; j < 4; ++j) {
      float4 v = s4[lane + 64 * j];
      ushort4 o = make_ushort4(f2bf(v.x), f2bf(v.y), f2bf(v.z), f2bf(v.w));
      d4[lane + 64 * j] = o;
      s += v.x * v.x + v.y * v.y + v.z * v.z + v.w * v.w;  // exact fp32 norms
    }
  } else {
    ushort4 z = make_ushort4(0, 0, 0, 0);
    #pragma unroll
    for (int j = 0; j < 4; ++j) d4[lane + 64 * j] = z;
  }
  #pragma unroll
  for (int off = 32; off > 0; off >>= 1) s += __shfl_down(s, off, 64);
  if (lane == 0) {
    sq[row] = (row < valid_rows) ? s : FLT_MAX;   // pad rows never win the min
    if (minbits && row < valid_rows) minbits[row] = 0x7F7FFFFFu;  // FLT_MAX bits
  }
}

// ---------- 2. bf16 MFMA GEMM + row-min: 256x256 tile, 4-slot LDS ring ----------
// 8 waves (2M x 4N), wave tile 128x64 (42.7 FLOP per LDS byte). BK=32.
// LDS: 4 ring slots x 32 KB (A 16K + B 16K), 128 KB dynamic.
// Staging: global_load_lds width=16, linear LDS dest; the XOR swizzle lives in
// the per-lane GLOBAL source address (rule: both-sides-or-neither). Chunk c
// (16B units) of a slot holds (row = (c&255)^(c>>8), koctet = c>>8); reads use
// chunk = q*256 + (row^q) -> 8-lane b128 phases hit 8 distinct bank groups.
// Schedule per K-tile t: [vmcnt(8); barrier; 12 ds_read_b128; stage tile t+3
// into slot (t-1)&3 (dead since this barrier); 32 MFMA in setprio(1)].
// Counted vmcnt: tiles t+1,t+2 stay in flight (8 calls) -> never drain to 0.
__global__ __launch_bounds__(512, 2) void gemm_min_kernel(
    const unsigned short* __restrict__ A,    // featB [6400][1024] bf16 bits
    const unsigned short* __restrict__ Bm,   // memB  [50176][1024] bf16 bits
    const float* __restrict__ f2, const float* __restrict__ m2,
    unsigned int* __restrict__ minbits)
{
  extern __shared__ char smem[];             // 4 * 32768 bytes

  // bijective XCD swizzle (nwg=4900: q=612, r=4) + 5x5 grouped tile walk:
  // consecutive wgids on one XCD share a 5-row M-group and walk N -> L2 holds
  // 5 A-tiles (2.5MB) + B-tile; B streamed ~5x total instead of 25x.
  const int orig = blockIdx.x;
  const int xcd  = orig & 7;
  const int wg   = ((xcd < 4) ? xcd * 613 : 2452 + (xcd - 4) * 612) + (orig >> 3);
  const int g    = wg / 980;                 // 980 = 5*196
  const int rem  = wg - g * 980;
  const int tileN = rem / 5;
  const int tileM = g * 5 + (rem - tileN * 5);

  const int tid  = threadIdx.x;
  const int w    = tid >> 6, lane = tid & 63;
  const int wr   = w >> 2, wc = w & 3;       // 2x4 wave grid, 128x64 per wave
  const int quad = lane >> 4, r16 = lane & 15;

  // staging: 4 global_load_lds per wave per tile (A blocks 2w,2w+1; B same).
  // wave-block m: q = m>>2 (k-octet), lane's global row = ((m&3)*64+lane)^q.
  const unsigned short* gA[2];
  const unsigned short* gB[2];
  int offA[2], offB[2];
  #pragma unroll
  for (int j = 0; j < 2; ++j) {
    const int m = w * 2 + j;
    const int q = m >> 2;
    const int row = ((m & 3) * 64 + lane) ^ q;
    gA[j] = A  + (size_t)(tileM * 256 + row) * C_DIM + q * 8;
    gB[j] = Bm + (size_t)(tileN * 256 + row) * C_DIM + q * 8;
    offA[j] = m * 1024;                      // byte offset of 64-chunk block
    offB[j] = 16384 + m * 1024;
  }

  auto stage = [&](int kt) {
    char* sl = smem + ((kt & 3) << 15);
    const int ko = kt * 32;                  // K offset in shorts
    #pragma unroll
    for (int j = 0; j < 2; ++j) {
      __builtin_amdgcn_global_load_lds(
        (const __attribute__((address_space(1))) unsigned int*)(gA[j] + ko),
        (__attribute__((address_space(3))) unsigned int*)(sl + offA[j]), 16, 0, 0);
      __builtin_amdgcn_global_load_lds(
        (const __attribute__((address_space(1))) unsigned int*)(gB[j] + ko),
        (__attribute__((address_space(3))) unsigned int*)(sl + offB[j]), 16, 0, 0);
    }
  };

  f32x4 acc[8][4] = {};
  const int aIdx0 = quad * 256 + wr * 128 + (r16 ^ quad);   // bf16x8 units
  const int bIdx0 = quad * 256 + wc * 64  + (r16 ^ quad);

  // prologue: 3 tiles in flight before first compute
  stage(0); stage(1); stage(2);

  auto body = [&](int kt, bool doStage) {
    __builtin_amdgcn_s_barrier();            // all waves' loads for slot kt&3 landed
    __builtin_amdgcn_sched_barrier(0);       // nothing crosses the barrier
    const bf16x8* LA = (const bf16x8*)(smem + ((kt & 3) << 15));
    const bf16x8* LB = (const bf16x8*)(smem + ((kt & 3) << 15) + 16384);
    bf16x8 a[8], b[4];
    #pragma unroll
    for (int i = 0; i < 8; ++i) a[i] = LA[aIdx0 + i * 16];
    #pragma unroll
    for (int j = 0; j < 4; ++j) b[j] = LB[bIdx0 + j * 16];
    if (doStage) stage(kt + 3);              // slot (kt-1)&3: dead since barrier
    __builtin_amdgcn_s_setprio(1);
    #pragma unroll
    for (int i = 0; i < 8; ++i)
      #pragma unroll
      for (int j = 0; j < 4; ++j)
        acc[i][j] = __builtin_amdgcn_mfma_f32_16x16x32_bf16(a[i], b[j], acc[i][j], 0, 0, 0);
    __builtin_amdgcn_s_setprio(0);
  };

  for (int kt = 0; kt < 30; ++kt) {
    asm volatile("s_waitcnt vmcnt(8)" ::: "memory");  // tiles kt+1,kt+2 stay in flight
    body(kt, kt < 29);
  }
  asm volatile("s_waitcnt vmcnt(4)" ::: "memory");
  body(30, false);
  asm volatile("s_waitcnt vmcnt(0)" ::: "memory");
  body(31, false);

  // epilogue: d2 = f2 + m2 - 2*dot, clamp >= 0, min over this wave's 64 cols
  const int colbase = tileN * 256 + wc * 64 + r16;
  float m2v[4];
  #pragma unroll
  for (int j = 0; j < 4; ++j) m2v[j] = m2[colbase + j * 16];
  const int rowq = tileM * 256 + wr * 128 + quad * 4;
  #pragma unroll
  for (int i = 0; i < 8; ++i) {
    #pragma unroll
    for (int r = 0; r < 4; ++r) {
      const int n = rowq + i * 16 + r;       // C/D: row = quad*4 + reg, col = r16
      const float f2v = f2[n];
      float best = FLT_MAX;
      #pragma unroll
      for (int j = 0; j < 4; ++j) {
        float d = f2v + m2v[j] - 2.0f * acc[i][j][r];
        d = fmaxf(d, 0.0f);                  // clamp-then-min == max(min,0)
        best = fminf(best, d);
      }
      best = fminf(best, __shfl_xor(best, 1, 64));
      best = fminf(best, __shfl_xor(best, 2, 64));
      best = fminf(best, __shfl_xor(best, 4, 64));
      best = fminf(best, __shfl_xor(best, 8, 64));
      if (r16 == 0) atomicMin(minbits + n, __float_as_uint(best));
    }
  }
}

// ---------- 3. sqrt + per-image max + 28x28 mask ----------
__global__ __launch_bounds__(256) void finalize_kernel(
    const unsigned int* __restrict__ minbits, float* __restrict__ m28,
    float* __restrict__ image_scores)
{
  int b = blockIdx.x, tid = threadIdx.x;
  float mx = 0.f;
  for (int i = tid; i < 784; i += 256) {
    float s = sqrtf(__uint_as_float(minbits[b * 784 + i]));
    m28[b * 784 + i] = s;
    mx = fmaxf(mx, s);
  }
  #pragma unroll
  for (int off = 32; off > 0; off >>= 1) mx = fmaxf(mx, __shfl_down(mx, off, 64));
  __shared__ float red[4];
  if ((tid & 63) == 0) red[tid >> 6] = mx;
  __syncthreads();
  if (tid == 0) image_scores[b] = fmaxf(fmaxf(red[0], red[1]), fmaxf(red[2], red[3]));
}

// ---------- 4. bilinear 28 -> 224 ----------
__global__ __launch_bounds__(256) void resize_kernel(
    const float* __restrict__ m28, float* __restrict__ out)
{
  int idx = blockIdx.x * 256 + threadIdx.x;
  if (idx >= B_IMG * IMGSZ * IMGSZ) return;
  int x = idx % IMGSZ, y = (idx / IMGSZ) % IMGSZ, b = idx / (IMGSZ * IMGSZ);
  float sy = (y + 0.5f) * 0.125f - 0.5f;
  float sx = (x + 0.5f) * 0.125f - 0.5f;
  int iy0 = (int)floorf(sy); float fy = sy - (float)iy0;
  int ix0 = (int)floorf(sx); float fx = sx - (float)ix0;
  int y0 = min(max(iy0, 0), 27), y1 = min(max(iy0 + 1, 0), 27);
  int x0 = min(max(ix0, 0), 27), x1 = min(max(ix0 + 1, 0), 27);
  const float* p = m28 + b * 784;
  float v00 = p[y0 * 28 + x0], v01 = p[y0 * 28 + x1];
  float v10 = p[y1 * 28 + x0], v11 = p[y1 * 28 + x1];
  out[idx] = (1.f - fy) * ((1.f - fx) * v00 + fx * v01) +
             fy         * ((1.f - fx) * v10 + fx * v11);
}

// ---------- 5. separable 17-tap gaussian, reflect padding ----------
__device__ inline void gauss17(float* g) {
  float s = 0.f;
  #pragma unroll
  for (int i = 0; i < 17; ++i) {
    float x = (float)(i - 8);
    g[i] = expf(-x * x * (1.0f / 32.0f));   // sigma=4 -> 2*sigma^2 = 32
    s += g[i];
  }
  float inv = 1.0f / s;
  #pragma unroll
  for (int i = 0; i < 17; ++i) g[i] *= inv;
}

__device__ inline int refl(int t) { return t < 0 ? -t : (t > 223 ? 446 - t : t); }

__global__ __launch_bounds__(256) void blur_h_kernel(
    const float* __restrict__ in, float* __restrict__ out)
{
  int idx = blockIdx.x * 256 + threadIdx.x;
  if (idx >= B_IMG * IMGSZ * IMGSZ) return;
  int x = idx % IMGSZ, y = (idx / IMGSZ) % IMGSZ, b = idx / (IMGSZ * IMGSZ);
  float g[17]; gauss17(g);
  const float* row = in + (size_t)b * IMGSZ * IMGSZ + y * IMGSZ;
  float s = 0.f;
  #pragma unroll
  for (int k = 0; k < 17; ++k) s += g[k] * row[refl(x + k - 8)];
  out[idx] = s;
}

__global__ __launch_bounds__(256) void blur_v_kernel(
    const float* __restrict__ in, float* __restrict__ out)
{
  int idx = blockIdx.x * 256 + threadIdx.x;
  if (idx >= B_IMG * IMGSZ * IMGSZ) return;
  int x = idx % IMGSZ, y = (idx / IMGSZ) % IMGSZ, b = idx / (IMGSZ * IMGSZ);
  float g[17]; gauss17(g);
  const float* img = in + (size_t)b * IMGSZ * IMGSZ;
  float s = 0.f;
  #pragma unroll
  for (int k = 0; k < 17; ++k) s += g[k] * img[refl(y + k - 8) * IMGSZ + x];
  out[idx] = s;
}

// ---------- launch ----------
extern "C" void kernel_launch(void* const* d_in, const int* in_sizes, int n_in,
                              void* d_out, int out_size, void* d_ws, size_t ws_size,
                              hipStream_t stream) {
  const float* features = (const float*)d_in[0];
  const float* memory   = (const float*)d_in[1];
  if (n_in >= 2 && in_sizes[0] > in_sizes[1]) {
    const float* t = features; features = memory; memory = t;
  }
  float* out = (float*)d_out;
  char* ws = (char*)d_ws;

  // workspace layout (rsz/tmp reuse the memB region, dead after gemm):
  unsigned short* memB  = (unsigned short*)(ws);                 // 102,760,448 B
  unsigned short* featB = (unsigned short*)(ws + 102760448);     //  13,107,200 B
  float*        f2      = (float*)(ws + 115867648);              //      25,600 B
  float*        m2      = (float*)(ws + 115893248);              //     200,704 B
  unsigned int* minb    = (unsigned int*)(ws + 116093952);       //      25,600 B
  float*        m28     = (float*)(ws + 116119552);              //      25,088 B
  float*        rsz     = (float*)(ws);                          // overlaps memB
  float*        tmp     = (float*)(ws + 1605632);                // overlaps memB

  static int attr_done = 0;
  if (!attr_done) {
    hipFuncSetAttribute((const void*)gemm_min_kernel,
                        hipFuncAttributeMaxDynamicSharedMemorySize, 131072);
    attr_done = 1;
  }

  convert_rows_kernel<<<M_PAD / 4, 256, 0, stream>>>(memory, memB, m2, nullptr, M_MEM, M_PAD);
  convert_rows_kernel<<<N_FPAD / 4, 256, 0, stream>>>(features, featB, f2, minb, N_FEAT, N_FPAD);

  gemm_min_kernel<<<NT, 512, 131072, stream>>>(featB, memB, f2, m2, minb);

  finalize_kernel<<<B_IMG, 256, 0, stream>>>(minb, m28, out);
  resize_kernel<<<(B_IMG * IMGSZ * IMGSZ) / 256, 256, 0, stream>>>(m28, rsz);
  blur_h_kernel<<<(B_IMG * IMGSZ * IMGSZ) / 256, 256, 0, stream>>>(rsz, tmp);
  blur_v_kernel<<<(B_IMG * IMGSZ * IMGSZ) / 256, 256, 0, stream>>>(tmp, out + 8);
}

// Round 2
// 1156.174 us; speedup vs baseline: 1.3364x; 1.3364x over previous
//
#include <hip/hip_runtime.h>
#include <hip/hip_bf16.h>
#include <float.h>

#define N_FEAT 6272      // B*FH*FW = 8*28*28
#define N_FPAD 6400      // 25 * 256
#define C_DIM  1024
#define M_MEM  50000
#define M_PAD  50176     // 196 * 256
#define B_IMG  8
#define IMGSZ  224
#define NTM    25        // 6400/256
#define NTN    196       // 50176/256
#define NT     4900      // 25*196

typedef __attribute__((ext_vector_type(8))) short bf16x8;
typedef __attribute__((ext_vector_type(4))) float f32x4;

// ---------- helpers ----------

__device__ inline unsigned short f2bf(float x) {
  unsigned int u = __float_as_uint(x);
  u += 0x7FFFu + ((u >> 16) & 1u);
  return (unsigned short)(u >> 16);
}

// ---------- 1. fp32 -> bf16 conversion + row sum-of-squares (1 wave / row) ----------
__global__ __launch_bounds__(256) void convert_rows_kernel(
    const float* __restrict__ src, unsigned short* __restrict__ dst,
    float* __restrict__ sq, unsigned int* __restrict__ minbits,
    int valid_rows, int total_rows)
{
  int row  = blockIdx.x * 4 + (threadIdx.x >> 6);
  int lane = threadIdx.x & 63;
  if (row >= total_rows) return;
  float s = 0.f;
  ushort4* d4 = (ushort4*)(dst + (size_t)row * C_DIM);
  if (row < valid_rows) {
    const float4* s4 = (const float4*)(src + (size_t)row * C_DIM);
    #pragma unroll
    for (int j = 0; j < 4; ++j) {
      float4 v = s4[lane + 64 * j];
      ushort4 o = make_ushort4(f2bf(v.x), f2bf(v.y), f2bf(v.z), f2bf(v.w));
      d4[lane + 64 * j] = o;
      s += v.x * v.x + v.y * v.y + v.z * v.z + v.w * v.w;  // exact fp32 norms
    }
  } else {
    ushort4 z = make_ushort4(0, 0, 0, 0);
    #pragma unroll
    for (int j = 0; j < 4; ++j) d4[lane + 64 * j] = z;
  }
  #pragma unroll
  for (int off = 32; off > 0; off >>= 1) s += __shfl_down(s, off, 64);
  if (lane == 0) {
    sq[row] = (row < valid_rows) ? s : FLT_MAX;   // pad rows never win the min
    if (minbits && row < valid_rows) minbits[row] = 0x7F7FFFFFu;  // FLT_MAX bits
  }
}

// ---------- 2. bf16 MFMA GEMM + row-min: 256x256 tile, 4-slot LDS ring ----------
// 8 waves (2M x 4N), wave tile 128x64. BK=32. LDS: 4 ring slots x 32 KB.
// Staging (the round-1 fix): lane = (row_block, k-octet) -> 4 consecutive lanes
// read one 64B row segment (512 L2 transactions/tile, was 2048 with the
// all-lanes-one-octet mapping that starved the DMA return path).
// Permutation (both-sides-or-neither): source octet q = (lane&3)^(row&3);
// linear gll dest means LDS chunk row*4+q' holds octet q'^(row&3); reader at
// (quad,row) fetches chunk row*4+(quad^(row&3)) -> gets octet quad. Read
// phases: 8 lanes span rows r..r+7 at 64B stride with octet-XOR spread ->
// max 2-way bank aliasing (free).
// Schedule per K-tile t: [vmcnt(8); barrier; stage t+3 into slot (t-1)&3
// (dead since this barrier); ds_read b+a0; 16 MFMA; ds_read a1; 16 MFMA].
// Counted vmcnt: tiles t+1,t+2 stay in flight -> never drain to 0 mid-loop.
__global__ __launch_bounds__(512, 2) void gemm_min_kernel(
    const unsigned short* __restrict__ A,    // featB [6400][1024] bf16 bits
    const unsigned short* __restrict__ Bm,   // memB  [50176][1024] bf16 bits
    const float* __restrict__ f2, const float* __restrict__ m2,
    unsigned int* __restrict__ minbits)
{
  extern __shared__ char smem[];             // 4 * 32768 bytes

  // bijective XCD swizzle (nwg=4900: q=612, r=4) + 5x5 grouped tile walk
  const int orig = blockIdx.x;
  const int xcd  = orig & 7;
  const int wg   = ((xcd < 4) ? xcd * 613 : 2452 + (xcd - 4) * 612) + (orig >> 3);
  const int g    = wg / 980;                 // 980 = 5*196
  const int rem  = wg - g * 980;
  const int tileN = rem / 5;
  const int tileM = g * 5 + (rem - tileN * 5);

  const int tid  = threadIdx.x;
  const int w    = tid >> 6, lane = tid & 63;
  const int wr   = w >> 2, wc = w & 3;       // 2x4 wave grid, 128x64 per wave
  const int quad = lane >> 4, r16 = lane & 15;

  // staging pointers: wave handles row-blocks m = 2w, 2w+1 of A and of B.
  // lane: rowInBlk = lane>>2, q' = lane&3, source octet q = q'^(rowInBlk&3).
  const unsigned short* gAp[2];
  const unsigned short* gBp[2];
  int offA[2], offB[2];
  {
    const int rowInBlk = lane >> 2;
    const int qsrc = (lane & 3) ^ (rowInBlk & 3);
    #pragma unroll
    for (int j = 0; j < 2; ++j) {
      const int m = w * 2 + j;
      const int row = m * 16 + rowInBlk;
      gAp[j] = A  + (size_t)(tileM * 256 + row) * C_DIM + qsrc * 8;
      gBp[j] = Bm + (size_t)(tileN * 256 + row) * C_DIM + qsrc * 8;
      offA[j] = m * 1024;                    // byte offset of 16-row block
      offB[j] = 16384 + m * 1024;
    }
  }

  auto stage = [&](int kt) {
    char* sl = smem + ((kt & 3) << 15);
    const int ko = kt * 32;                  // K offset in shorts
    #pragma unroll
    for (int j = 0; j < 2; ++j) {
      __builtin_amdgcn_global_load_lds(
        (const __attribute__((address_space(1))) unsigned int*)(gAp[j] + ko),
        (__attribute__((address_space(3))) unsigned int*)(sl + offA[j]), 16, 0, 0);
      __builtin_amdgcn_global_load_lds(
        (const __attribute__((address_space(1))) unsigned int*)(gBp[j] + ko),
        (__attribute__((address_space(3))) unsigned int*)(sl + offB[j]), 16, 0, 0);
    }
  };

  f32x4 acc[8][4] = {};
  // fragment chunk indices (16B units): chunk(row) = row*4 + (quad^(row&3));
  // row&3 == r16&3 for all rows we touch (offsets are multiples of 16).
  const int fsw   = quad ^ (r16 & 3);
  const int aBase = (wr * 128 + r16) * 4 + fsw;   // + i*64 per 16-row step
  const int bBase = (wc * 64  + r16) * 4 + fsw;

  // prologue: 3 tiles in flight before first compute
  stage(0); stage(1); stage(2);

  auto body = [&](int kt, bool doStage) {
    __builtin_amdgcn_s_barrier();            // slot kt&3 fully written
    __builtin_amdgcn_sched_barrier(0);       // nothing crosses the barrier
    if (doStage) stage(kt + 3);              // slot (kt-1)&3: dead since barrier
    const char* base = smem + ((kt & 3) << 15);
    const bf16x8* LA = (const bf16x8*)base;
    const bf16x8* LB = (const bf16x8*)(base + 16384);
    bf16x8 b[4], a[4];
    #pragma unroll
    for (int j = 0; j < 4; ++j) b[j] = LB[bBase + j * 64];
    #pragma unroll
    for (int i = 0; i < 4; ++i) a[i] = LA[aBase + i * 64];
    __builtin_amdgcn_s_setprio(1);
    #pragma unroll
    for (int i = 0; i < 4; ++i)
      #pragma unroll
      for (int j = 0; j < 4; ++j)
        acc[i][j] = __builtin_amdgcn_mfma_f32_16x16x32_bf16(a[i], b[j], acc[i][j], 0, 0, 0);
    __builtin_amdgcn_s_setprio(0);
    bf16x8 a2[4];
    #pragma unroll
    for (int i = 0; i < 4; ++i) a2[i] = LA[aBase + (i + 4) * 64];
    __builtin_amdgcn_s_setprio(1);
    #pragma unroll
    for (int i = 0; i < 4; ++i)
      #pragma unroll
      for (int j = 0; j < 4; ++j)
        acc[i + 4][j] = __builtin_amdgcn_mfma_f32_16x16x32_bf16(a2[i], b[j], acc[i + 4][j], 0, 0, 0);
    __builtin_amdgcn_s_setprio(0);
  };

  for (int kt = 0; kt < 30; ++kt) {
    asm volatile("s_waitcnt vmcnt(8)" ::: "memory");  // tiles kt+1,kt+2 in flight
    body(kt, kt < 29);
  }
  asm volatile("s_waitcnt vmcnt(4)" ::: "memory");
  body(30, false);
  asm volatile("s_waitcnt vmcnt(0)" ::: "memory");
  body(31, false);

  // epilogue: d2 = f2 + m2 - 2*dot, clamp >= 0, min over this wave's 64 cols
  const int colbase = tileN * 256 + wc * 64 + r16;
  float m2v[4];
  #pragma unroll
  for (int j = 0; j < 4; ++j) m2v[j] = m2[colbase + j * 16];
  const int rowq = tileM * 256 + wr * 128 + quad * 4;
  #pragma unroll
  for (int i = 0; i < 8; ++i) {
    #pragma unroll
    for (int r = 0; r < 4; ++r) {
      const int n = rowq + i * 16 + r;       // C/D: row = quad*4 + reg, col = r16
      const float f2v = f2[n];
      float best = FLT_MAX;
      #pragma unroll
      for (int j = 0; j < 4; ++j) {
        float d = f2v + m2v[j] - 2.0f * acc[i][j][r];
        d = fmaxf(d, 0.0f);                  // clamp-then-min == max(min,0)
        best = fminf(best, d);
      }
      best = fminf(best, __shfl_xor(best, 1, 64));
      best = fminf(best, __shfl_xor(best, 2, 64));
      best = fminf(best, __shfl_xor(best, 4, 64));
      best = fminf(best, __shfl_xor(best, 8, 64));
      if (r16 == 0) atomicMin(minbits + n, __float_as_uint(best));
    }
  }
}

// ---------- 3. sqrt + per-image max + 28x28 mask ----------
__global__ __launch_bounds__(256) void finalize_kernel(
    const unsigned int* __restrict__ minbits, float* __restrict__ m28,
    float* __restrict__ image_scores)
{
  int b = blockIdx.x, tid = threadIdx.x;
  float mx = 0.f;
  for (int i = tid; i < 784; i += 256) {
    float s = sqrtf(__uint_as_float(minbits[b * 784 + i]));
    m28[b * 784 + i] = s;
    mx = fmaxf(mx, s);
  }
  #pragma unroll
  for (int off = 32; off > 0; off >>= 1) mx = fmaxf(mx, __shfl_down(mx, off, 64));
  __shared__ float red[4];
  if ((tid & 63) == 0) red[tid >> 6] = mx;
  __syncthreads();
  if (tid == 0) image_scores[b] = fmaxf(fmaxf(red[0], red[1]), fmaxf(red[2], red[3]));
}

// ---------- 4. bilinear 28 -> 224 ----------
__global__ __launch_bounds__(256) void resize_kernel(
    const float* __restrict__ m28, float* __restrict__ out)
{
  int idx = blockIdx.x * 256 + threadIdx.x;
  if (idx >= B_IMG * IMGSZ * IMGSZ) return;
  int x = idx % IMGSZ, y = (idx / IMGSZ) % IMGSZ, b = idx / (IMGSZ * IMGSZ);
  float sy = (y + 0.5f) * 0.125f - 0.5f;
  float sx = (x + 0.5f) * 0.125f - 0.5f;
  int iy0 = (int)floorf(sy); float fy = sy - (float)iy0;
  int ix0 = (int)floorf(sx); float fx = sx - (float)ix0;
  int y0 = min(max(iy0, 0), 27), y1 = min(max(iy0 + 1, 0), 27);
  int x0 = min(max(ix0, 0), 27), x1 = min(max(ix0 + 1, 0), 27);
  const float* p = m28 + b * 784;
  float v00 = p[y0 * 28 + x0], v01 = p[y0 * 28 + x1];
  float v10 = p[y1 * 28 + x0], v11 = p[y1 * 28 + x1];
  out[idx] = (1.f - fy) * ((1.f - fx) * v00 + fx * v01) +
             fy         * ((1.f - fx) * v10 + fx * v11);
}

// ---------- 5. separable 17-tap gaussian, reflect padding ----------
__device__ inline void gauss17(float* g) {
  float s = 0.f;
  #pragma unroll
  for (int i = 0; i < 17; ++i) {
    float x = (float)(i - 8);
    g[i] = expf(-x * x * (1.0f / 32.0f));   // sigma=4 -> 2*sigma^2 = 32
    s += g[i];
  }
  float inv = 1.0f / s;
  #pragma unroll
  for (int i = 0; i < 17; ++i) g[i] *= inv;
}

__device__ inline int refl(int t) { return t < 0 ? -t : (t > 223 ? 446 - t : t); }

__global__ __launch_bounds__(256) void blur_h_kernel(
    const float* __restrict__ in, float* __restrict__ out)
{
  int idx = blockIdx.x * 256 + threadIdx.x;
  if (idx >= B_IMG * IMGSZ * IMGSZ) return;
  int x = idx % IMGSZ, y = (idx / IMGSZ) % IMGSZ, b = idx / (IMGSZ * IMGSZ);
  float g[17]; gauss17(g);
  const float* row = in + (size_t)b * IMGSZ * IMGSZ + y * IMGSZ;
  float s = 0.f;
  #pragma unroll
  for (int k = 0; k < 17; ++k) s += g[k] * row[refl(x + k - 8)];
  out[idx] = s;
}

__global__ __launch_bounds__(256) void blur_v_kernel(
    const float* __restrict__ in, float* __restrict__ out)
{
  int idx = blockIdx.x * 256 + threadIdx.x;
  if (idx >= B_IMG * IMGSZ * IMGSZ) return;
  int x = idx % IMGSZ, y = (idx / IMGSZ) % IMGSZ, b = idx / (IMGSZ * IMGSZ);
  float g[17]; gauss17(g);
  const float* img = in + (size_t)b * IMGSZ * IMGSZ;
  float s = 0.f;
  #pragma unroll
  for (int k = 0; k < 17; ++k) s += g[k] * img[refl(y + k - 8) * IMGSZ + x];
  out[idx] = s;
}

// ---------- launch ----------
extern "C" void kernel_launch(void* const* d_in, const int* in_sizes, int n_in,
                              void* d_out, int out_size, void* d_ws, size_t ws_size,
                              hipStream_t stream) {
  const float* features = (const float*)d_in[0];
  const float* memory   = (const float*)d_in[1];
  if (n_in >= 2 && in_sizes[0] > in_sizes[1]) {
    const float* t = features; features = memory; memory = t;
  }
  float* out = (float*)d_out;
  char* ws = (char*)d_ws;

  // workspace layout (rsz/tmp reuse the memB region, dead after gemm):
  unsigned short* memB  = (unsigned short*)(ws);                 // 102,760,448 B
  unsigned short* featB = (unsigned short*)(ws + 102760448);     //  13,107,200 B
  float*        f2      = (float*)(ws + 115867648);              //      25,600 B
  float*        m2      = (float*)(ws + 115893248);              //     200,704 B
  unsigned int* minb    = (unsigned int*)(ws + 116093952);       //      25,600 B
  float*        m28     = (float*)(ws + 116119552);              //      25,088 B
  float*        rsz     = (float*)(ws);                          // overlaps memB
  float*        tmp     = (float*)(ws + 1605632);                // overlaps memB

  static int attr_done = 0;
  if (!attr_done) {
    hipFuncSetAttribute((const void*)gemm_min_kernel,
                        hipFuncAttributeMaxDynamicSharedMemorySize, 131072);
    attr_done = 1;
  }

  convert_rows_kernel<<<M_PAD / 4, 256, 0, stream>>>(memory, memB, m2, nullptr, M_MEM, M_PAD);
  convert_rows_kernel<<<N_FPAD / 4, 256, 0, stream>>>(features, featB, f2, minb, N_FEAT, N_FPAD);

  gemm_min_kernel<<<NT, 512, 131072, stream>>>(featB, memB, f2, m2, minb);

  finalize_kernel<<<B_IMG, 256, 0, stream>>>(minb, m28, out);
  resize_kernel<<<(B_IMG * IMGSZ * IMGSZ) / 256, 256, 0, stream>>>(m28, rsz);
  blur_h_kernel<<<(B_IMG * IMGSZ * IMGSZ) / 256, 256, 0, stream>>>(rsz, tmp);
  blur_v_kernel<<<(B_IMG * IMGSZ * IMGSZ) / 256, 256, 0, stream>>>(tmp, out + 8);
}

// Round 3
// 1096.912 us; speedup vs baseline: 1.4086x; 1.0540x over previous
//
#include <hip/hip_runtime.h>
#include <hip/hip_bf16.h>
#include <float.h>

#define N_FEAT 6272      // B*FH*FW = 8*28*28
#define N_FPAD 6400      // 25 * 256
#define C_DIM  1024
#define M_MEM  50000
#define M_PAD  50176     // 196 * 256
#define B_IMG  8
#define IMGSZ  224
#define NTM    25        // 6400/256
#define NTN    196       // 50176/256
#define NT     4900      // 25*196

typedef __attribute__((ext_vector_type(8))) short bf16x8;
typedef __attribute__((ext_vector_type(4))) float f32x4;

// ---------- helpers ----------

__device__ inline unsigned short f2bf(float x) {
  unsigned int u = __float_as_uint(x);
  u += 0x7FFFu + ((u >> 16) & 1u);
  return (unsigned short)(u >> 16);
}

// ---------- 1. fp32 -> bf16 conversion + row sum-of-squares (1 wave / row) ----------
__global__ __launch_bounds__(256) void convert_rows_kernel(
    const float* __restrict__ src, unsigned short* __restrict__ dst,
    float* __restrict__ sq, unsigned int* __restrict__ minbits,
    int valid_rows, int total_rows)
{
  int row  = blockIdx.x * 4 + (threadIdx.x >> 6);
  int lane = threadIdx.x & 63;
  if (row >= total_rows) return;
  float s = 0.f;
  ushort4* d4 = (ushort4*)(dst + (size_t)row * C_DIM);
  if (row < valid_rows) {
    const float4* s4 = (const float4*)(src + (size_t)row * C_DIM);
    #pragma unroll
    for (int j = 0; j < 4; ++j) {
      float4 v = s4[lane + 64 * j];
      ushort4 o = make_ushort4(f2bf(v.x), f2bf(v.y), f2bf(v.z), f2bf(v.w));
      d4[lane + 64 * j] = o;
      s += v.x * v.x + v.y * v.y + v.z * v.z + v.w * v.w;  // exact fp32 norms
    }
  } else {
    ushort4 z = make_ushort4(0, 0, 0, 0);
    #pragma unroll
    for (int j = 0; j < 4; ++j) d4[lane + 64 * j] = z;
  }
  #pragma unroll
  for (int off = 32; off > 0; off >>= 1) s += __shfl_down(s, off, 64);
  if (lane == 0) {
    sq[row] = (row < valid_rows) ? s : FLT_MAX;   // pad rows never win the min
    if (minbits && row < valid_rows) minbits[row] = 0x7F7FFFFFu;  // FLT_MAX bits
  }
}

// ---------- 2. bf16 MFMA GEMM + row-min: 256x256 tile, 4-slot LDS ring ----------
// 8 waves (2M x 4N), wave tile 128x64. BK=32. LDS: 4 ring slots x 32 KB.
// Staging: 4 consecutive lanes read one 64B row segment (round-1 fix kept).
// Involution (round-2 fix): source octet q' = (lane&3) ^ h(lane>>2) with
// h(r) = (r>>1)&3; linear gll dest => chunk row*4 + x holds octet x^h(row&15);
// reader at (quad,row) fetches chunk row*4 + (quad^h(row&15)).
// Bank groups per 8-lane b128 phase: 4*(r16&1) + (quad^h(r16)) runs over all
// 8 groups for any 8 consecutive r16 -> conflict-free (the r&3 variant only
// hit 4 groups twice each = the 6.0e7 conflict cycles seen in round 2).
// Schedule per K-tile t (2 phases, m201 pacing):
//   vmcnt(8); BARRIER; stage t+3 -> slot (t-1)&3 (all waves' reads of that
//   slot completed before this barrier: lgkm-drained before their phase-2
//   MFMAs); ds_read b0..3,a0..3; 16 MFMA @prio1; ds_read a4..7; BARRIER;
//   16 MFMA @prio1.
// Counted vmcnt: tiles t+1,t+2 stay in flight -> never drain to 0 mid-loop.
__global__ __launch_bounds__(512, 2) void gemm_min_kernel(
    const unsigned short* __restrict__ A,    // featB [6400][1024] bf16 bits
    const unsigned short* __restrict__ Bm,   // memB  [50176][1024] bf16 bits
    const float* __restrict__ f2, const float* __restrict__ m2,
    unsigned int* __restrict__ minbits)
{
  extern __shared__ char smem[];             // 4 * 32768 bytes

  // bijective XCD swizzle (nwg=4900: q=612, r=4) + 5x5 grouped tile walk
  const int orig = blockIdx.x;
  const int xcd  = orig & 7;
  const int wg   = ((xcd < 4) ? xcd * 613 : 2452 + (xcd - 4) * 612) + (orig >> 3);
  const int g    = wg / 980;                 // 980 = 5*196
  const int rem  = wg - g * 980;
  const int tileN = rem / 5;
  const int tileM = g * 5 + (rem - tileN * 5);

  const int tid  = threadIdx.x;
  const int w    = tid >> 6, lane = tid & 63;
  const int wr   = w >> 2, wc = w & 3;       // 2x4 wave grid, 128x64 per wave
  const int quad = lane >> 4, r16 = lane & 15;

  // staging pointers: wave handles row-blocks m = 2w, 2w+1 of A and of B.
  // lane: rowInBlk = lane>>2, source octet = (lane&3) ^ ((lane>>3)&3).
  const unsigned short* gAp[2];
  const unsigned short* gBp[2];
  int offA[2], offB[2];
  {
    const int rowInBlk = lane >> 2;
    const int qsrc = (lane & 3) ^ ((lane >> 3) & 3);   // (lane&3) ^ h(rowInBlk)
    #pragma unroll
    for (int j = 0; j < 2; ++j) {
      const int m = w * 2 + j;
      const int row = m * 16 + rowInBlk;
      gAp[j] = A  + (size_t)(tileM * 256 + row) * C_DIM + qsrc * 8;
      gBp[j] = Bm + (size_t)(tileN * 256 + row) * C_DIM + qsrc * 8;
      offA[j] = m * 1024;                    // byte offset of 16-row block
      offB[j] = 16384 + m * 1024;
    }
  }

  auto stage = [&](int kt) {
    char* sl = smem + ((kt & 3) << 15);
    const int ko = kt * 32;                  // K offset in shorts
    #pragma unroll
    for (int j = 0; j < 2; ++j) {
      __builtin_amdgcn_global_load_lds(
        (const __attribute__((address_space(1))) unsigned int*)(gAp[j] + ko),
        (__attribute__((address_space(3))) unsigned int*)(sl + offA[j]), 16, 0, 0);
      __builtin_amdgcn_global_load_lds(
        (const __attribute__((address_space(1))) unsigned int*)(gBp[j] + ko),
        (__attribute__((address_space(3))) unsigned int*)(sl + offB[j]), 16, 0, 0);
    }
  };

  f32x4 acc[8][4] = {};
  // fragment chunk indices (16B units): chunk(row,quad) = row*4 + (quad^h(r16))
  const int fsw   = quad ^ ((r16 >> 1) & 3);
  const int aBase = (wr * 128 + r16) * 4 + fsw;   // + i*64 per 16-row step
  const int bBase = (wc * 64  + r16) * 4 + fsw;

  // prologue: 3 tiles in flight before first compute
  stage(0); stage(1); stage(2);

  auto body = [&](int kt, bool doStage) {
    __builtin_amdgcn_s_barrier();            // slot kt&3 fully written; all
    __builtin_amdgcn_sched_barrier(0);       //   reads of slot (kt-1)&3 done
    if (doStage) stage(kt + 3);              // -> safe to overwrite (kt-1)&3
    const char* base = smem + ((kt & 3) << 15);
    const bf16x8* LA = (const bf16x8*)base;
    const bf16x8* LB = (const bf16x8*)(base + 16384);
    bf16x8 b[4], a[4];
    #pragma unroll
    for (int j = 0; j < 4; ++j) b[j] = LB[bBase + j * 64];
    #pragma unroll
    for (int i = 0; i < 4; ++i) a[i] = LA[aBase + i * 64];
    __builtin_amdgcn_s_setprio(1);
    #pragma unroll
    for (int i = 0; i < 4; ++i)
      #pragma unroll
      for (int j = 0; j < 4; ++j)
        acc[i][j] = __builtin_amdgcn_mfma_f32_16x16x32_bf16(a[i], b[j], acc[i][j], 0, 0, 0);
    __builtin_amdgcn_s_setprio(0);
    bf16x8 a2[4];
    #pragma unroll
    for (int i = 0; i < 4; ++i) a2[i] = LA[aBase + (i + 4) * 64];
    __builtin_amdgcn_s_barrier();            // pacing: phase split (reads of
    __builtin_amdgcn_sched_barrier(0);       //   next phase already in flight)
    __builtin_amdgcn_s_setprio(1);
    #pragma unroll
    for (int i = 0; i < 4; ++i)
      #pragma unroll
      for (int j = 0; j < 4; ++j)
        acc[i + 4][j] = __builtin_amdgcn_mfma_f32_16x16x32_bf16(a2[i], b[j], acc[i + 4][j], 0, 0, 0);
    __builtin_amdgcn_s_setprio(0);
  };

  for (int kt = 0; kt < 30; ++kt) {
    asm volatile("s_waitcnt vmcnt(8)" ::: "memory");  // tiles kt+1,kt+2 in flight
    body(kt, kt < 29);
  }
  asm volatile("s_waitcnt vmcnt(4)" ::: "memory");
  body(30, false);
  asm volatile("s_waitcnt vmcnt(0)" ::: "memory");
  body(31, false);

  // epilogue: d2 = f2 + m2 - 2*dot, clamp >= 0, min over this wave's 64 cols
  const int colbase = tileN * 256 + wc * 64 + r16;
  float m2v[4];
  #pragma unroll
  for (int j = 0; j < 4; ++j) m2v[j] = m2[colbase + j * 16];
  const int rowq = tileM * 256 + wr * 128 + quad * 4;
  #pragma unroll
  for (int i = 0; i < 8; ++i) {
    #pragma unroll
    for (int r = 0; r < 4; ++r) {
      const int n = rowq + i * 16 + r;       // C/D: row = quad*4 + reg, col = r16
      const float f2v = f2[n];
      float best = FLT_MAX;
      #pragma unroll
      for (int j = 0; j < 4; ++j) {
        float d = f2v + m2v[j] - 2.0f * acc[i][j][r];
        d = fmaxf(d, 0.0f);                  // clamp-then-min == max(min,0)
        best = fminf(best, d);
      }
      best = fminf(best, __shfl_xor(best, 1, 64));
      best = fminf(best, __shfl_xor(best, 2, 64));
      best = fminf(best, __shfl_xor(best, 4, 64));
      best = fminf(best, __shfl_xor(best, 8, 64));
      if (r16 == 0) atomicMin(minbits + n, __float_as_uint(best));
    }
  }
}

// ---------- 3. sqrt + per-image max + 28x28 mask ----------
__global__ __launch_bounds__(256) void finalize_kernel(
    const unsigned int* __restrict__ minbits, float* __restrict__ m28,
    float* __restrict__ image_scores)
{
  int b = blockIdx.x, tid = threadIdx.x;
  float mx = 0.f;
  for (int i = tid; i < 784; i += 256) {
    float s = sqrtf(__uint_as_float(minbits[b * 784 + i]));
    m28[b * 784 + i] = s;
    mx = fmaxf(mx, s);
  }
  #pragma unroll
  for (int off = 32; off > 0; off >>= 1) mx = fmaxf(mx, __shfl_down(mx, off, 64));
  __shared__ float red[4];
  if ((tid & 63) == 0) red[tid >> 6] = mx;
  __syncthreads();
  if (tid == 0) image_scores[b] = fmaxf(fmaxf(red[0], red[1]), fmaxf(red[2], red[3]));
}

// ---------- 4. bilinear 28 -> 224 ----------
__global__ __launch_bounds__(256) void resize_kernel(
    const float* __restrict__ m28, float* __restrict__ out)
{
  int idx = blockIdx.x * 256 + threadIdx.x;
  if (idx >= B_IMG * IMGSZ * IMGSZ) return;
  int x = idx % IMGSZ, y = (idx / IMGSZ) % IMGSZ, b = idx / (IMGSZ * IMGSZ);
  float sy = (y + 0.5f) * 0.125f - 0.5f;
  float sx = (x + 0.5f) * 0.125f - 0.5f;
  int iy0 = (int)floorf(sy); float fy = sy - (float)iy0;
  int ix0 = (int)floorf(sx); float fx = sx - (float)ix0;
  int y0 = min(max(iy0, 0), 27), y1 = min(max(iy0 + 1, 0), 27);
  int x0 = min(max(ix0, 0), 27), x1 = min(max(ix0 + 1, 0), 27);
  const float* p = m28 + b * 784;
  float v00 = p[y0 * 28 + x0], v01 = p[y0 * 28 + x1];
  float v10 = p[y1 * 28 + x0], v11 = p[y1 * 28 + x1];
  out[idx] = (1.f - fy) * ((1.f - fx) * v00 + fx * v01) +
             fy         * ((1.f - fx) * v10 + fx * v11);
}

// ---------- 5. separable 17-tap gaussian, reflect padding ----------
__device__ inline void gauss17(float* g) {
  float s = 0.f;
  #pragma unroll
  for (int i = 0; i < 17; ++i) {
    float x = (float)(i - 8);
    g[i] = expf(-x * x * (1.0f / 32.0f));   // sigma=4 -> 2*sigma^2 = 32
    s += g[i];
  }
  float inv = 1.0f / s;
  #pragma unroll
  for (int i = 0; i < 17; ++i) g[i] *= inv;
}

__device__ inline int refl(int t) { return t < 0 ? -t : (t > 223 ? 446 - t : t); }

__global__ __launch_bounds__(256) void blur_h_kernel(
    const float* __restrict__ in, float* __restrict__ out)
{
  int idx = blockIdx.x * 256 + threadIdx.x;
  if (idx >= B_IMG * IMGSZ * IMGSZ) return;
  int x = idx % IMGSZ, y = (idx / IMGSZ) % IMGSZ, b = idx / (IMGSZ * IMGSZ);
  float g[17]; gauss17(g);
  const float* row = in + (size_t)b * IMGSZ * IMGSZ + y * IMGSZ;
  float s = 0.f;
  #pragma unroll
  for (int k = 0; k < 17; ++k) s += g[k] * row[refl(x + k - 8)];
  out[idx] = s;
}

__global__ __launch_bounds__(256) void blur_v_kernel(
    const float* __restrict__ in, float* __restrict__ out)
{
  int idx = blockIdx.x * 256 + threadIdx.x;
  if (idx >= B_IMG * IMGSZ * IMGSZ) return;
  int x = idx % IMGSZ, y = (idx / IMGSZ) % IMGSZ, b = idx / (IMGSZ * IMGSZ);
  float g[17]; gauss17(g);
  const float* img = in + (size_t)b * IMGSZ * IMGSZ;
  float s = 0.f;
  #pragma unroll
  for (int k = 0; k < 17; ++k) s += g[k] * img[refl(y + k - 8) * IMGSZ + x];
  out[idx] = s;
}

// ---------- launch ----------
extern "C" void kernel_launch(void* const* d_in, const int* in_sizes, int n_in,
                              void* d_out, int out_size, void* d_ws, size_t ws_size,
                              hipStream_t stream) {
  const float* features = (const float*)d_in[0];
  const float* memory   = (const float*)d_in[1];
  if (n_in >= 2 && in_sizes[0] > in_sizes[1]) {
    const float* t = features; features = memory; memory = t;
  }
  float* out = (float*)d_out;
  char* ws = (char*)d_ws;

  // workspace layout (rsz/tmp reuse the memB region, dead after gemm):
  unsigned short* memB  = (unsigned short*)(ws);                 // 102,760,448 B
  unsigned short* featB = (unsigned short*)(ws + 102760448);     //  13,107,200 B
  float*        f2      = (float*)(ws + 115867648);              //      25,600 B
  float*        m2      = (float*)(ws + 115893248);              //     200,704 B
  unsigned int* minb    = (unsigned int*)(ws + 116093952);       //      25,600 B
  float*        m28     = (float*)(ws + 116119552);              //      25,088 B
  float*        rsz     = (float*)(ws);                          // overlaps memB
  float*        tmp     = (float*)(ws + 1605632);                // overlaps memB

  static int attr_done = 0;
  if (!attr_done) {
    hipFuncSetAttribute((const void*)gemm_min_kernel,
                        hipFuncAttributeMaxDynamicSharedMemorySize, 131072);
    attr_done = 1;
  }

  convert_rows_kernel<<<M_PAD / 4, 256, 0, stream>>>(memory, memB, m2, nullptr, M_MEM, M_PAD);
  convert_rows_kernel<<<N_FPAD / 4, 256, 0, stream>>>(features, featB, f2, minb, N_FEAT, N_FPAD);

  gemm_min_kernel<<<NT, 512, 131072, stream>>>(featB, memB, f2, m2, minb);

  finalize_kernel<<<B_IMG, 256, 0, stream>>>(minb, m28, out);
  resize_kernel<<<(B_IMG * IMGSZ * IMGSZ) / 256, 256, 0, stream>>>(m28, rsz);
  blur_h_kernel<<<(B_IMG * IMGSZ * IMGSZ) / 256, 256, 0, stream>>>(rsz, tmp);
  blur_v_kernel<<<(B_IMG * IMGSZ * IMGSZ) / 256, 256, 0, stream>>>(tmp, out + 8);
}